// Round 1
// baseline (2213.099 us; speedup 1.0000x reference)
//
#include <hip/hip_runtime.h>
#include <hip/hip_bf16.h>
#include <math.h>

#define B_   2
#define S_   2048
#define H_   1024
#define NH_  16
#define HD_  64
#define DFF_ 4096
#define ROWS (B_*S_)   // 4096
#define EPS_ 1e-6f

// ---------------------------------------------------------------------------
// LayerNorm: one block per row, 256 threads, float4 per thread (H=1024)
// ---------------------------------------------------------------------------
__global__ __launch_bounds__(256) void ln_kernel(const float* __restrict__ x,
                                                 const float* __restrict__ g,
                                                 const float* __restrict__ b,
                                                 float* __restrict__ y) {
    int row = blockIdx.x;
    int t = threadIdx.x;
    const float4* xr = reinterpret_cast<const float4*>(x + (size_t)row * H_);
    float4 v = xr[t];
    float s  = v.x + v.y + v.z + v.w;
    float ss = v.x*v.x + v.y*v.y + v.z*v.z + v.w*v.w;
    #pragma unroll
    for (int m = 1; m < 64; m <<= 1) {
        s  += __shfl_xor(s,  m, 64);
        ss += __shfl_xor(ss, m, 64);
    }
    __shared__ float ws_s[4], ws_ss[4];
    int wid = t >> 6;
    if ((t & 63) == 0) { ws_s[wid] = s; ws_ss[wid] = ss; }
    __syncthreads();
    s  = ws_s[0] + ws_s[1] + ws_s[2] + ws_s[3];
    ss = ws_ss[0] + ws_ss[1] + ws_ss[2] + ws_ss[3];
    float mu   = s * (1.0f / H_);
    float var  = ss * (1.0f / H_) - mu * mu;
    float rstd = rsqrtf(var + EPS_);
    float4 gv = reinterpret_cast<const float4*>(g)[t];
    float4 bv = reinterpret_cast<const float4*>(b)[t];
    float4 o;
    o.x = (v.x - mu) * rstd * gv.x + bv.x;
    o.y = (v.y - mu) * rstd * gv.y + bv.y;
    o.z = (v.z - mu) * rstd * gv.z + bv.z;
    o.w = (v.w - mu) * rstd * gv.w + bv.w;
    reinterpret_cast<float4*>(y + (size_t)row * H_)[t] = o;
}

// ---------------------------------------------------------------------------
// NT GEMM: C[M,N] = A[M,K] @ B[N,K]^T (+bias)(+gelu)(+res)
// 64x64 tile, BK=16, 256 threads, 4x4 micro-tile per thread.
// ---------------------------------------------------------------------------
enum { EP_NONE = 0, EP_RES = 1, EP_BIAS_GELU = 2, EP_BIAS_RES = 3 };

template<int EPI>
__global__ __launch_bounds__(256) void gemm_nt(const float* __restrict__ A,
                                               const float* __restrict__ Bm,
                                               float* __restrict__ C,
                                               const float* __restrict__ bias,
                                               const float* __restrict__ res,
                                               int M, int N, int K) {
    const int BM = 64, BN = 64, BK = 16;
    __shared__ float As[BK][BM + 4];   // stride 68 floats: float4-aligned
    __shared__ float Bs[BK][BN + 4];
    int t  = threadIdx.x;
    int bm = blockIdx.y * BM;
    int bn = blockIdx.x * BN;
    int tr = t >> 4;        // 0..15
    int tc = t & 15;        // 0..15
    int lr = t >> 2;        // 0..63  (tile row loaded)
    int lk = (t & 3) * 4;   // 0,4,8,12

    float acc[4][4] = {};

    for (int k0 = 0; k0 < K; k0 += BK) {
        float4 a4 = *reinterpret_cast<const float4*>(A  + (size_t)(bm + lr) * K + k0 + lk);
        float4 b4 = *reinterpret_cast<const float4*>(Bm + (size_t)(bn + lr) * K + k0 + lk);
        As[lk+0][lr] = a4.x; As[lk+1][lr] = a4.y; As[lk+2][lr] = a4.z; As[lk+3][lr] = a4.w;
        Bs[lk+0][lr] = b4.x; Bs[lk+1][lr] = b4.y; Bs[lk+2][lr] = b4.z; Bs[lk+3][lr] = b4.w;
        __syncthreads();
        #pragma unroll
        for (int kk = 0; kk < BK; ++kk) {
            float4 av = *reinterpret_cast<const float4*>(&As[kk][tr * 4]);
            float4 bv = *reinterpret_cast<const float4*>(&Bs[kk][tc * 4]);
            float a[4] = {av.x, av.y, av.z, av.w};
            float b[4] = {bv.x, bv.y, bv.z, bv.w};
            #pragma unroll
            for (int i = 0; i < 4; ++i)
                #pragma unroll
                for (int j = 0; j < 4; ++j)
                    acc[i][j] = fmaf(a[i], b[j], acc[i][j]);
        }
        __syncthreads();
    }

    // epilogue: rows bm+tr*4+i, cols bn+tc*4+j (4 contiguous -> float4 store)
    #pragma unroll
    for (int i = 0; i < 4; ++i) {
        int r = bm + tr * 4 + i;
        int c = bn + tc * 4;
        size_t idx = (size_t)r * N + c;
        float val[4];
        #pragma unroll
        for (int j = 0; j < 4; ++j) val[j] = acc[i][j];
        if (EPI == EP_BIAS_GELU || EPI == EP_BIAS_RES) {
            float4 bb = *reinterpret_cast<const float4*>(bias + c);
            val[0] += bb.x; val[1] += bb.y; val[2] += bb.z; val[3] += bb.w;
        }
        if (EPI == EP_BIAS_GELU) {
            #pragma unroll
            for (int j = 0; j < 4; ++j)
                val[j] = 0.5f * val[j] * (1.0f + erff(val[j] * 0.70710678118654752f));
        }
        if (EPI == EP_RES || EPI == EP_BIAS_RES) {
            float4 rr = *reinterpret_cast<const float4*>(res + idx);
            val[0] += rr.x; val[1] += rr.y; val[2] += rr.z; val[3] += rr.w;
        }
        float4 o = make_float4(val[0], val[1], val[2], val[3]);
        *reinterpret_cast<float4*>(C + idx) = o;
    }
}

// ---------------------------------------------------------------------------
// Causal flash attention, fp32. Block = 32 q-rows of one (b,h). 256 threads:
// thread t -> q-row r=t>>3, group-lane tg=t&7. Online softmax; K/V in LDS.
// ---------------------------------------------------------------------------
__global__ __launch_bounds__(256) void attn_kernel(const float* __restrict__ qkv,
                                                   float* __restrict__ ctx) {
    int qt = blockIdx.x;   // q tile 0..63
    int h  = blockIdx.y;   // head 0..15
    int b  = blockIdx.z;   // batch 0..1
    int t  = threadIdx.x;

    __shared__ float Qs[32][HD_ + 4];
    __shared__ float Ks[32][HD_ + 4];
    __shared__ float Vs[32][HD_ + 4];
    __shared__ float Ps[32][32 + 4];

    int r  = t >> 3;       // 0..31 q row in tile
    int tg = t & 7;        // 0..7
    int lr = t >> 3;       // loader row
    int ld = (t & 7) * 8;  // loader col base (2 float4s)

    const size_t rstride = 3 * H_;
    size_t qbase = ((size_t)(b * S_) + (size_t)qt * 32 + lr) * rstride + h * HD_;
    *reinterpret_cast<float4*>(&Qs[lr][ld])     = *reinterpret_cast<const float4*>(qkv + qbase + ld);
    *reinterpret_cast<float4*>(&Qs[lr][ld + 4]) = *reinterpret_cast<const float4*>(qkv + qbase + ld + 4);

    float m_run = -1e30f, l_run = 0.0f;
    float acc[8] = {0,0,0,0,0,0,0,0};
    int qi = qt * 32 + r;

    for (int kt = 0; kt <= qt; ++kt) {
        __syncthreads();
        size_t kbase = ((size_t)(b * S_) + (size_t)kt * 32 + lr) * rstride + H_ + h * HD_;
        size_t vbase = kbase + H_;
        *reinterpret_cast<float4*>(&Ks[lr][ld])     = *reinterpret_cast<const float4*>(qkv + kbase + ld);
        *reinterpret_cast<float4*>(&Ks[lr][ld + 4]) = *reinterpret_cast<const float4*>(qkv + kbase + ld + 4);
        *reinterpret_cast<float4*>(&Vs[lr][ld])     = *reinterpret_cast<const float4*>(qkv + vbase + ld);
        *reinterpret_cast<float4*>(&Vs[lr][ld + 4]) = *reinterpret_cast<const float4*>(qkv + vbase + ld + 4);
        __syncthreads();

        // scores for cols c = tg*4 .. tg*4+3
        float s[4] = {0, 0, 0, 0};
        #pragma unroll
        for (int d4 = 0; d4 < 16; ++d4) {
            float4 q4 = *reinterpret_cast<const float4*>(&Qs[r][d4 * 4]);
            #pragma unroll
            for (int c = 0; c < 4; ++c) {
                float4 k4 = *reinterpret_cast<const float4*>(&Ks[tg * 4 + c][d4 * 4]);
                s[c] = fmaf(q4.x, k4.x, s[c]);
                s[c] = fmaf(q4.y, k4.y, s[c]);
                s[c] = fmaf(q4.z, k4.z, s[c]);
                s[c] = fmaf(q4.w, k4.w, s[c]);
            }
        }
        const float scale = 0.125f;   // 64^-0.5
        int kb = kt * 32;
        #pragma unroll
        for (int c = 0; c < 4; ++c) {
            int ki = kb + tg * 4 + c;
            s[c] = (ki <= qi) ? s[c] * scale : -1e30f;
        }
        float mt = fmaxf(fmaxf(s[0], s[1]), fmaxf(s[2], s[3]));
        mt = fmaxf(mt, __shfl_xor(mt, 1, 64));
        mt = fmaxf(mt, __shfl_xor(mt, 2, 64));
        mt = fmaxf(mt, __shfl_xor(mt, 4, 64));
        float m_new = fmaxf(m_run, mt);
        float p[4], psum = 0.0f;
        #pragma unroll
        for (int c = 0; c < 4; ++c) { p[c] = __expf(s[c] - m_new); psum += p[c]; }
        psum += __shfl_xor(psum, 1, 64);
        psum += __shfl_xor(psum, 2, 64);
        psum += __shfl_xor(psum, 4, 64);
        float alpha = __expf(m_run - m_new);
        l_run = l_run * alpha + psum;
        m_run = m_new;
        *reinterpret_cast<float4*>(&Ps[r][tg * 4]) = make_float4(p[0], p[1], p[2], p[3]);
        __syncthreads();

        // PV: thread owns d = tg*8 .. tg*8+7
        #pragma unroll
        for (int i = 0; i < 8; ++i) acc[i] *= alpha;
        #pragma unroll
        for (int c = 0; c < 32; ++c) {
            float pc  = Ps[r][c];
            float4 v0 = *reinterpret_cast<const float4*>(&Vs[c][tg * 8]);
            float4 v1 = *reinterpret_cast<const float4*>(&Vs[c][tg * 8 + 4]);
            acc[0] = fmaf(pc, v0.x, acc[0]);
            acc[1] = fmaf(pc, v0.y, acc[1]);
            acc[2] = fmaf(pc, v0.z, acc[2]);
            acc[3] = fmaf(pc, v0.w, acc[3]);
            acc[4] = fmaf(pc, v1.x, acc[4]);
            acc[5] = fmaf(pc, v1.y, acc[5]);
            acc[6] = fmaf(pc, v1.z, acc[6]);
            acc[7] = fmaf(pc, v1.w, acc[7]);
        }
    }

    float inv_l = 1.0f / l_run;
    float4 o0 = make_float4(acc[0] * inv_l, acc[1] * inv_l, acc[2] * inv_l, acc[3] * inv_l);
    float4 o1 = make_float4(acc[4] * inv_l, acc[5] * inv_l, acc[6] * inv_l, acc[7] * inv_l);
    size_t obase = ((size_t)(b * S_) + (size_t)qt * 32 + r) * H_ + h * HD_ + tg * 8;
    *reinterpret_cast<float4*>(ctx + obase)     = o0;
    *reinterpret_cast<float4*>(ctx + obase + 4) = o1;
}

// ---------------------------------------------------------------------------
extern "C" void kernel_launch(void* const* d_in, const int* in_sizes, int n_in,
                              void* d_out, int out_size, void* d_ws, size_t ws_size,
                              hipStream_t stream) {
    const float* x     = (const float*)d_in[0];
    // d_in[1] = attention_mask (bool, causal) -- structure known, ignored
    const float* ln1_g = (const float*)d_in[2];
    const float* ln1_b = (const float*)d_in[3];
    const float* ln2_g = (const float*)d_in[4];
    const float* ln2_b = (const float*)d_in[5];
    const float* qkv_w = (const float*)d_in[6];
    const float* out_w = (const float*)d_in[7];
    const float* fc1_w = (const float*)d_in[8];
    const float* fc1_b = (const float*)d_in[9];
    const float* fc2_w = (const float*)d_in[10];
    const float* fc2_b = (const float*)d_in[11];
    float* out = (float*)d_out;

    float* buf_h   = (float*)d_ws;                       // ROWS*H      (16 MB)
    float* buf_qkv = buf_h   + (size_t)ROWS * H_;        // ROWS*3H     (48 MB)
    float* buf_ctx = buf_qkv + (size_t)ROWS * 3 * H_;    // ROWS*H      (16 MB)
    float* buf_ff  = buf_ctx + (size_t)ROWS * H_;        // ROWS*DFF    (64 MB)

    // 1. h = LN1(x)
    ln_kernel<<<ROWS, 256, 0, stream>>>(x, ln1_g, ln1_b, buf_h);
    // 2. qkv = h @ qkv_w^T            [4096, 3072]
    gemm_nt<EP_NONE><<<dim3(3 * H_ / 64, ROWS / 64), 256, 0, stream>>>(
        buf_h, qkv_w, buf_qkv, nullptr, nullptr, ROWS, 3 * H_, H_);
    // 3. ctx = causal_attention(q,k,v)
    attn_kernel<<<dim3(S_ / 32, NH_, B_), 256, 0, stream>>>(buf_qkv, buf_ctx);
    // 4. x1 = x + ctx @ out_w^T  -> d_out
    gemm_nt<EP_RES><<<dim3(H_ / 64, ROWS / 64), 256, 0, stream>>>(
        buf_ctx, out_w, out, nullptr, x, ROWS, H_, H_);
    // 5. h2 = LN2(x1)
    ln_kernel<<<ROWS, 256, 0, stream>>>(out, ln2_g, ln2_b, buf_h);
    // 6. ff = gelu(h2 @ fc1_w^T + fc1_b)   [4096, 4096]
    gemm_nt<EP_BIAS_GELU><<<dim3(DFF_ / 64, ROWS / 64), 256, 0, stream>>>(
        buf_h, fc1_w, buf_ff, fc1_b, nullptr, ROWS, DFF_, H_);
    // 7. out = x1 + ff @ fc2_w^T + fc2_b   (reads d_out as residual, same-thread RMW)
    gemm_nt<EP_BIAS_RES><<<dim3(H_ / 64, ROWS / 64), 256, 0, stream>>>(
        buf_ff, fc2_w, out, fc2_b, out, ROWS, H_, DFF_);
}

// Round 3
// 409.412 us; speedup vs baseline: 5.4056x; 5.4056x over previous
//
#include <hip/hip_runtime.h>
#include <hip/hip_bf16.h>
#include <math.h>

#define B_   2
#define S_   2048
#define H_   1024
#define NH_  16
#define HD_  64
#define DFF_ 4096
#define ROWS (B_*S_)   // 4096
#define EPS_ 1e-6f

typedef __hip_bfloat16 bf16;
typedef __attribute__((ext_vector_type(8))) short s8;      // 8 x bf16 (4 VGPR) MFMA frag
typedef __attribute__((ext_vector_type(4))) float f32x4;   // MFMA accumulator

__device__ __forceinline__ bf16 to_bf16(float f) { return __float2bfloat16(f); }

#define GLOAD_LDS16(g, l) __builtin_amdgcn_global_load_lds( \
    (const __attribute__((address_space(1))) void*)(g),     \
    (__attribute__((address_space(3))) void*)(l), 16, 0, 0)

// ---------------------------------------------------------------------------
// float -> bf16 cast, 8 elements/thread
// ---------------------------------------------------------------------------
__global__ __launch_bounds__(256) void cast_bf16_k(const float* __restrict__ in,
                                                   bf16* __restrict__ out, int n) {
    int i = (blockIdx.x * 256 + threadIdx.x) * 8;
    if (i >= n) return;
    float4 a = *reinterpret_cast<const float4*>(in + i);
    float4 b = *reinterpret_cast<const float4*>(in + i + 4);
    union { bf16 h[8]; s8 v; } u;
    u.h[0] = to_bf16(a.x); u.h[1] = to_bf16(a.y); u.h[2] = to_bf16(a.z); u.h[3] = to_bf16(a.w);
    u.h[4] = to_bf16(b.x); u.h[5] = to_bf16(b.y); u.h[6] = to_bf16(b.z); u.h[7] = to_bf16(b.w);
    *reinterpret_cast<s8*>(out + i) = u.v;
}

// ---------------------------------------------------------------------------
// LayerNorm fp32 -> bf16, one block per row (H=1024), 256 threads x float4
// ---------------------------------------------------------------------------
__global__ __launch_bounds__(256) void ln_bf16(const float* __restrict__ x,
                                               const float* __restrict__ g,
                                               const float* __restrict__ b,
                                               bf16* __restrict__ y) {
    int row = blockIdx.x;
    int t = threadIdx.x;
    float4 v = reinterpret_cast<const float4*>(x + (size_t)row * H_)[t];
    float s  = v.x + v.y + v.z + v.w;
    float ss = v.x*v.x + v.y*v.y + v.z*v.z + v.w*v.w;
    #pragma unroll
    for (int m = 1; m < 64; m <<= 1) {
        s  += __shfl_xor(s,  m, 64);
        ss += __shfl_xor(ss, m, 64);
    }
    __shared__ float ws_s[4], ws_ss[4];
    int wid = t >> 6;
    if ((t & 63) == 0) { ws_s[wid] = s; ws_ss[wid] = ss; }
    __syncthreads();
    s  = ws_s[0] + ws_s[1] + ws_s[2] + ws_s[3];
    ss = ws_ss[0] + ws_ss[1] + ws_ss[2] + ws_ss[3];
    float mu   = s * (1.0f / H_);
    float var  = ss * (1.0f / H_) - mu * mu;
    float rstd = rsqrtf(var + EPS_);
    float4 gv = reinterpret_cast<const float4*>(g)[t];
    float4 bv = reinterpret_cast<const float4*>(b)[t];
    union { bf16 h[4]; short4 sv; } u;
    u.h[0] = to_bf16((v.x - mu) * rstd * gv.x + bv.x);
    u.h[1] = to_bf16((v.y - mu) * rstd * gv.y + bv.y);
    u.h[2] = to_bf16((v.z - mu) * rstd * gv.z + bv.z);
    u.h[3] = to_bf16((v.w - mu) * rstd * gv.w + bv.w);
    *reinterpret_cast<short4*>(y + (size_t)row * H_ + t * 4) = u.sv;
}

// ---------------------------------------------------------------------------
// bf16 MFMA NT GEMM: C[M,N] = A[M,K] @ B[N,K]^T, fp32 accum.
// 128x128 tile, BK=64, 256 threads (4 waves, 2x2 of 64x64), global_load_lds.
// EPI: 0 = qkv (bf16 out; V-part written transposed to vT)
//      1 = fp32 out + res
//      2 = bf16 out, +bias, exact GELU
//      3 = fp32 out, +bias, +res
// ---------------------------------------------------------------------------
template<int EPI>
__global__ __launch_bounds__(256, 2) void gemm_bf16(const bf16* __restrict__ A,
                                                    const bf16* __restrict__ Bw,
                                                    bf16* __restrict__ Cb,
                                                    float* __restrict__ Cf,
                                                    bf16* __restrict__ vT,
                                                    const float* __restrict__ bias,
                                                    const float* __restrict__ res,
                                                    int M, int N, int K, int GX) {
    __shared__ bf16 As[128 * 64];
    __shared__ bf16 Bs[128 * 64];

    // XCD-aware swizzle (grid size always % 8 == 0 here)
    int nwg = gridDim.x;
    int ld  = blockIdx.x;
    int wgid = (ld & 7) * (nwg >> 3) + (ld >> 3);
    int by = wgid / GX, bx = wgid % GX;

    int t = threadIdx.x, l = t & 63, w = t >> 6;
    int lr = l & 15, lg = l >> 4;
    size_t bm = (size_t)by * 128, bn = (size_t)bx * 128;

    int srow = t >> 3;           // 0..31
    int skb  = (t & 7) * 8;      // k elem offset
    const bf16* Ag = A  + (bm + srow) * K + skb;
    const bf16* Bg = Bw + (bn + srow) * K + skb;
    bf16* Asw = As + w * 512;    // per-wave uniform LDS base
    bf16* Bsw = Bs + w * 512;

    int wr = (w >> 1) << 6, wc = (w & 1) << 6;

    f32x4 acc[4][4];
    const f32x4 z4 = {0.f, 0.f, 0.f, 0.f};
    #pragma unroll
    for (int i = 0; i < 4; ++i)
        #pragma unroll
        for (int j = 0; j < 4; ++j) acc[i][j] = z4;

    for (int k0 = 0; k0 < K; k0 += 64) {
        const bf16* Ak = Ag + k0;
        const bf16* Bk = Bg + k0;
        #pragma unroll
        for (int c = 0; c < 4; ++c)
            GLOAD_LDS16(Ak + (size_t)c * 32 * K, Asw + c * 2048);
        #pragma unroll
        for (int c = 0; c < 4; ++c)
            GLOAD_LDS16(Bk + (size_t)c * 32 * K, Bsw + c * 2048);
        asm volatile("s_waitcnt vmcnt(0)" ::: "memory");
        __syncthreads();
        #pragma unroll
        for (int kk = 0; kk < 64; kk += 32) {
            s8 af[4], bfr[4];
            #pragma unroll
            for (int i = 0; i < 4; ++i)
                af[i] = *reinterpret_cast<const s8*>(As + (wr + i*16 + lr) * 64 + kk + lg * 8);
            #pragma unroll
            for (int j = 0; j < 4; ++j)
                bfr[j] = *reinterpret_cast<const s8*>(Bs + (wc + j*16 + lr) * 64 + kk + lg * 8);
            #pragma unroll
            for (int i = 0; i < 4; ++i)
                #pragma unroll
                for (int j = 0; j < 4; ++j)
                    acc[i][j] = __builtin_amdgcn_mfma_f32_16x16x32_bf16(af[i], bfr[j], acc[i][j], 0, 0, 0);
        }
        __syncthreads();
    }

    // epilogue: row = bm+wr+i*16+lg*4+q, col = bn+wc+j*16+lr
    float bias_v[4];
    if (EPI == 2 || EPI == 3) {
        #pragma unroll
        for (int j = 0; j < 4; ++j) bias_v[j] = bias[bn + wc + j*16 + lr];
    }
    #pragma unroll
    for (int i = 0; i < 4; ++i) {
        #pragma unroll
        for (int q = 0; q < 4; ++q) {
            size_t rg = bm + wr + i*16 + lg*4 + q;
            #pragma unroll
            for (int j = 0; j < 4; ++j) {
                size_t cg = bn + wc + j*16 + lr;
                float v = acc[i][j][q];
                if (EPI == 0) {
                    if (cg < 2048) {
                        Cb[rg * N + cg] = to_bf16(v);
                    } else {
                        int hd = (int)cg - 2048;
                        int hh = hd >> 6, d = hd & 63;
                        int bb = (int)(rg >> 11), sq = (int)(rg & 2047);
                        vT[(((size_t)(bb * NH_ + hh)) * HD_ + d) * S_ + sq] = to_bf16(v);
                    }
                } else if (EPI == 1) {
                    Cf[rg * N + cg] = v + res[rg * N + cg];
                } else if (EPI == 2) {
                    float u = v + bias_v[j];
                    u = 0.5f * u * (1.0f + erff(u * 0.70710678118654752f));
                    Cb[rg * N + cg] = to_bf16(u);
                } else {
                    Cf[rg * N + cg] = v + bias_v[j] + res[rg * N + cg];
                }
            }
        }
    }
}

// ---------------------------------------------------------------------------
// MFMA flash attention (causal). Block = 64 q-rows of one (b,h); 4 waves x 16
// rows. KVBLK=32. K staged row-major [32][72] (padded), V pre-transposed in
// global (vT) staged to [64][40], P per-wave [16][40]. fp32 online softmax.
// ---------------------------------------------------------------------------
__global__ __launch_bounds__(256) void attn_mfma(const bf16* __restrict__ qkvb,
                                                 const bf16* __restrict__ vT,
                                                 bf16* __restrict__ ctx) {
    int qt = blockIdx.x, h = blockIdx.y, b = blockIdx.z;
    int t = threadIdx.x, l = t & 63, w = t >> 6;
    int lr = l & 15, lg = l >> 4;

    __shared__ bf16 Ks[32 * 72];
    __shared__ bf16 Vt[64 * 40];
    __shared__ bf16 Pw[4][16 * 40];

    int qb = qt * 64;
    const bf16* qp = qkvb + ((size_t)(b * S_) + qb + w * 16 + lr) * (3 * H_) + h * HD_;
    s8 qf0 = *reinterpret_cast<const s8*>(qp + lg * 8);
    s8 qf1 = *reinterpret_cast<const s8*>(qp + 32 + lg * 8);

    const f32x4 z4 = {0.f, 0.f, 0.f, 0.f};
    f32x4 oacc[4];
    #pragma unroll
    for (int n = 0; n < 4; ++n) oacc[n] = z4;
    float m_run[4] = {-1e30f, -1e30f, -1e30f, -1e30f};
    float l_run[4] = {0.f, 0.f, 0.f, 0.f};

    int skv = t >> 3, sd = (t & 7) * 8;     // K staging: row skv, dims sd..sd+7
    int vdim = t >> 2, vkb = (t & 3) * 8;   // V staging: dim vdim, kv vkb..vkb+7
    const bf16* kbase = qkvb + ((size_t)(b * S_) + skv) * (3 * H_) + H_ + h * HD_ + sd;
    const bf16* vbase = vT + ((size_t)((b * NH_ + h) * HD_ + vdim)) * S_ + vkb;

    int ntiles = qb / 32 + 2;
    for (int kt = 0; kt < ntiles; ++kt) {
        s8 kreg = *reinterpret_cast<const s8*>(kbase + (size_t)kt * 32 * (3 * H_));
        s8 vreg = *reinterpret_cast<const s8*>(vbase + kt * 32);
        __syncthreads();   // prior tile's reads complete before overwrite
        *reinterpret_cast<s8*>(&Ks[skv * 72 + sd]) = kreg;
        *reinterpret_cast<s8*>(&Vt[vdim * 40 + vkb]) = vreg;
        __syncthreads();

        // scores: S[16 rows][32 kv] per wave, via 2 col-groups x 2 k-steps
        f32x4 sa[2];
        #pragma unroll
        for (int n = 0; n < 2; ++n) {
            f32x4 zz = z4;
            s8 kf0 = *reinterpret_cast<const s8*>(&Ks[(n*16 + lr) * 72 + lg * 8]);
            s8 kf1 = *reinterpret_cast<const s8*>(&Ks[(n*16 + lr) * 72 + 32 + lg * 8]);
            zz = __builtin_amdgcn_mfma_f32_16x16x32_bf16(qf0, kf0, zz, 0, 0, 0);
            zz = __builtin_amdgcn_mfma_f32_16x16x32_bf16(qf1, kf1, zz, 0, 0, 0);
            sa[n] = zz;
        }

        int kvb0 = kt * 32;
        float p0[4], p1[4], mt[4], psum[4], al[4];
        #pragma unroll
        for (int q = 0; q < 4; ++q) {
            int qrow = qb + w * 16 + lg * 4 + q;
            float s0 = sa[0][q] * 0.125f;
            float s1 = sa[1][q] * 0.125f;
            if (kvb0 + lr > qrow)      s0 = -1e30f;
            if (kvb0 + 16 + lr > qrow) s1 = -1e30f;
            p0[q] = s0; p1[q] = s1;
            mt[q] = fmaxf(s0, s1);
        }
        #pragma unroll
        for (int m = 1; m < 16; m <<= 1) {
            #pragma unroll
            for (int q = 0; q < 4; ++q) mt[q] = fmaxf(mt[q], __shfl_xor(mt[q], m, 64));
        }
        #pragma unroll
        for (int q = 0; q < 4; ++q) {
            float mn = fmaxf(m_run[q], mt[q]);
            al[q] = __expf(m_run[q] - mn);
            m_run[q] = mn;
            float e0 = __expf(p0[q] - mn);
            float e1 = __expf(p1[q] - mn);
            p0[q] = e0; p1[q] = e1;
            psum[q] = e0 + e1;
        }
        #pragma unroll
        for (int m = 1; m < 16; m <<= 1) {
            #pragma unroll
            for (int q = 0; q < 4; ++q) psum[q] += __shfl_xor(psum[q], m, 64);
        }
        #pragma unroll
        for (int q = 0; q < 4; ++q) {
            l_run[q] = l_run[q] * al[q] + psum[q];
            #pragma unroll
            for (int n = 0; n < 4; ++n) oacc[n][q] *= al[q];
            Pw[w][(lg*4 + q) * 40 + lr]      = to_bf16(p0[q]);
            Pw[w][(lg*4 + q) * 40 + 16 + lr] = to_bf16(p1[q]);
        }
        asm volatile("s_waitcnt lgkmcnt(0)" ::: "memory");
        __builtin_amdgcn_sched_barrier(0);

        // PV: O[16][64] += P[16][32] @ V[32][64]
        s8 pf = *reinterpret_cast<const s8*>(&Pw[w][lr * 40 + lg * 8]);
        #pragma unroll
        for (int n = 0; n < 4; ++n) {
            s8 vf = *reinterpret_cast<const s8*>(&Vt[(n*16 + lr) * 40 + lg * 8]);
            oacc[n] = __builtin_amdgcn_mfma_f32_16x16x32_bf16(pf, vf, oacc[n], 0, 0, 0);
        }
    }

    #pragma unroll
    for (int q = 0; q < 4; ++q) {
        float inv = 1.0f / l_run[q];
        size_t row = (size_t)(b * S_) + qb + w * 16 + lg * 4 + q;
        #pragma unroll
        for (int n = 0; n < 4; ++n)
            ctx[row * H_ + h * HD_ + n * 16 + lr] = to_bf16(oacc[n][q] * inv);
    }
}

// ---------------------------------------------------------------------------
extern "C" void kernel_launch(void* const* d_in, const int* in_sizes, int n_in,
                              void* d_out, int out_size, void* d_ws, size_t ws_size,
                              hipStream_t stream) {
    const float* x     = (const float*)d_in[0];
    const float* ln1_g = (const float*)d_in[2];
    const float* ln1_b = (const float*)d_in[3];
    const float* ln2_g = (const float*)d_in[4];
    const float* ln2_b = (const float*)d_in[5];
    const float* qkv_w = (const float*)d_in[6];
    const float* out_w = (const float*)d_in[7];
    const float* fc1_w = (const float*)d_in[8];
    const float* fc1_b = (const float*)d_in[9];
    const float* fc2_w = (const float*)d_in[10];
    const float* fc2_b = (const float*)d_in[11];
    float* out = (float*)d_out;

    bf16* w_qkv  = (bf16*)d_ws;                       // 3,145,728
    bf16* w_out  = w_qkv  + (size_t)3*H_*H_;          // 1,048,576
    bf16* w_fc1  = w_out  + (size_t)H_*H_;            // 4,194,304
    bf16* w_fc2  = w_fc1  + (size_t)DFF_*H_;          // 4,194,304
    bf16* h_bf   = w_fc2  + (size_t)H_*DFF_;          // 4,194,304
    bf16* qkv_bf = h_bf   + (size_t)ROWS*H_;          // 12,582,912
    bf16* vTb    = qkv_bf + (size_t)ROWS*3*H_;        // 4,194,304
    bf16* ctx_bf = vTb    + (size_t)B_*NH_*HD_*S_;    // 4,194,304
    bf16* ff_bf  = ctx_bf + (size_t)ROWS*H_;          // 16,777,216

    // weight casts
    cast_bf16_k<<<(3*H_*H_)/2048, 256, 0, stream>>>(qkv_w, w_qkv, 3*H_*H_);
    cast_bf16_k<<<(H_*H_)/2048,   256, 0, stream>>>(out_w, w_out, H_*H_);
    cast_bf16_k<<<(DFF_*H_)/2048, 256, 0, stream>>>(fc1_w, w_fc1, DFF_*H_);
    cast_bf16_k<<<(H_*DFF_)/2048, 256, 0, stream>>>(fc2_w, w_fc2, H_*DFF_);

    // 1. h = LN1(x) -> bf16
    ln_bf16<<<ROWS, 256, 0, stream>>>(x, ln1_g, ln1_b, h_bf);
    // 2. qkv = h @ qkv_w^T  (Q,K row-major bf16; V written transposed to vT)
    gemm_bf16<0><<<32 * 24, 256, 0, stream>>>(h_bf, w_qkv, qkv_bf, nullptr, vTb,
                                              nullptr, nullptr, ROWS, 3*H_, H_, 24);
    // 3. ctx = causal flash attention (bf16 MFMA)
    attn_mfma<<<dim3(S_/64, NH_, B_), 256, 0, stream>>>(qkv_bf, vTb, ctx_bf);
    // 4. x1 = x + ctx @ out_w^T -> d_out (fp32)
    gemm_bf16<1><<<32 * 8, 256, 0, stream>>>(ctx_bf, w_out, nullptr, out, nullptr,
                                             nullptr, x, ROWS, H_, H_, 8);
    // 5. h2 = LN2(x1) -> bf16
    ln_bf16<<<ROWS, 256, 0, stream>>>(out, ln2_g, ln2_b, h_bf);
    // 6. ff = gelu(h2 @ fc1_w^T + fc1_b) -> bf16
    gemm_bf16<2><<<32 * 32, 256, 0, stream>>>(h_bf, w_fc1, ff_bf, nullptr, nullptr,
                                              fc1_b, nullptr, ROWS, DFF_, H_, 32);
    // 7. out = x1 + ff @ fc2_w^T + fc2_b (fp32, reads d_out as residual)
    gemm_bf16<3><<<32 * 8, 256, 0, stream>>>(ff_bf, w_fc2, nullptr, out, nullptr,
                                             fc2_b, out, ROWS, H_, DFF_, 8);
}

// Round 5
// 300.974 us; speedup vs baseline: 7.3531x; 1.3603x over previous
//
#include <hip/hip_runtime.h>
#include <hip/hip_bf16.h>
#include <math.h>

#define B_   2
#define S_   2048
#define H_   1024
#define NH_  16
#define HD_  64
#define DFF_ 4096
#define ROWS (B_*S_)   // 4096
#define EPS_ 1e-6f
#define NQT  (S_/64)   // 32 q-tiles of 64 rows

typedef __hip_bfloat16 bf16;
typedef __attribute__((ext_vector_type(8))) short s8;      // 8 x bf16 (4 VGPR) MFMA frag
typedef __attribute__((ext_vector_type(4))) float f32x4;   // MFMA accumulator

__device__ __forceinline__ bf16 to_bf16(float f) { return __float2bfloat16(f); }

#define GLOAD_LDS16(g, l) __builtin_amdgcn_global_load_lds( \
    (const __attribute__((address_space(1))) void*)(g),     \
    (__attribute__((address_space(3))) void*)(l), 16, 0, 0)

// ---------------------------------------------------------------------------
// Fused float -> bf16 cast of all 4 weight matrices, 8 elements/thread.
// ---------------------------------------------------------------------------
__global__ __launch_bounds__(256) void cast_all(const float* __restrict__ w0,
                                                const float* __restrict__ w1,
                                                const float* __restrict__ w2,
                                                const float* __restrict__ w3,
                                                bf16* __restrict__ o0, bf16* __restrict__ o1,
                                                bf16* __restrict__ o2, bf16* __restrict__ o3) {
    size_t u = (size_t)blockIdx.x * 256 + threadIdx.x;   // 8-elem unit
    const size_t n0 = (size_t)3*H_*H_/8, n1 = (size_t)H_*H_/8, n2 = (size_t)DFF_*H_/8;
    const float* src; bf16* dst; size_t base;
    if (u < n0)              { src = w0; dst = o0; base = u; }
    else if (u < n0+n1)      { src = w1; dst = o1; base = u-n0; }
    else if (u < n0+n1+n2)   { src = w2; dst = o2; base = u-n0-n1; }
    else                     { src = w3; dst = o3; base = u-n0-n1-n2; }
    size_t i = base * 8;
    float4 a = *reinterpret_cast<const float4*>(src + i);
    float4 b = *reinterpret_cast<const float4*>(src + i + 4);
    union { bf16 h[8]; s8 v; } uu;
    uu.h[0]=to_bf16(a.x); uu.h[1]=to_bf16(a.y); uu.h[2]=to_bf16(a.z); uu.h[3]=to_bf16(a.w);
    uu.h[4]=to_bf16(b.x); uu.h[5]=to_bf16(b.y); uu.h[6]=to_bf16(b.z); uu.h[7]=to_bf16(b.w);
    *reinterpret_cast<s8*>(dst + i) = uu.v;
}

// ---------------------------------------------------------------------------
// LayerNorm fp32 -> bf16, one block per row (H=1024), 256 threads x float4
// ---------------------------------------------------------------------------
__global__ __launch_bounds__(256) void ln_bf16(const float* __restrict__ x,
                                               const float* __restrict__ g,
                                               const float* __restrict__ b,
                                               bf16* __restrict__ y) {
    int row = blockIdx.x;
    int t = threadIdx.x;
    float4 v = reinterpret_cast<const float4*>(x + (size_t)row * H_)[t];
    float s  = v.x + v.y + v.z + v.w;
    float ss = v.x*v.x + v.y*v.y + v.z*v.z + v.w*v.w;
    #pragma unroll
    for (int m = 1; m < 64; m <<= 1) {
        s  += __shfl_xor(s,  m, 64);
        ss += __shfl_xor(ss, m, 64);
    }
    __shared__ float ws_s[4], ws_ss[4];
    int wid = t >> 6;
    if ((t & 63) == 0) { ws_s[wid] = s; ws_ss[wid] = ss; }
    __syncthreads();
    s  = ws_s[0] + ws_s[1] + ws_s[2] + ws_s[3];
    ss = ws_ss[0] + ws_ss[1] + ws_ss[2] + ws_ss[3];
    float mu   = s * (1.0f / H_);
    float var  = ss * (1.0f / H_) - mu * mu;
    float rstd = rsqrtf(var + EPS_);
    float4 gv = reinterpret_cast<const float4*>(g)[t];
    float4 bv = reinterpret_cast<const float4*>(b)[t];
    union { bf16 h[4]; short4 sv; } u;
    u.h[0] = to_bf16((v.x - mu) * rstd * gv.x + bv.x);
    u.h[1] = to_bf16((v.y - mu) * rstd * gv.y + bv.y);
    u.h[2] = to_bf16((v.z - mu) * rstd * gv.z + bv.z);
    u.h[3] = to_bf16((v.w - mu) * rstd * gv.w + bv.w);
    *reinterpret_cast<short4*>(y + (size_t)row * H_ + t * 4) = u.sv;
}

// ---------------------------------------------------------------------------
// bf16 MFMA NT GEMM: C[M,N] = A[M,K] @ B[N,K]^T, fp32 accum.
// 128xTN tile, BK=64, 256 threads (4 waves, 2x2), global_load_lds width 16.
// TN in {128, 64}. EPI: 0 = qkv (bf16 out; V-part transposed to vT)
//                       1 = fp32 out + res
//                       2 = bf16 out, +bias, exact GELU
//                       3 = fp32 out, +bias, +res
// ---------------------------------------------------------------------------
template<int EPI, int TN>
__global__ __launch_bounds__(256, 2) void gemm_bf16(const bf16* __restrict__ A,
                                                    const bf16* __restrict__ Bw,
                                                    bf16* __restrict__ Cb,
                                                    float* __restrict__ Cf,
                                                    bf16* __restrict__ vT,
                                                    const float* __restrict__ bias,
                                                    const float* __restrict__ res,
                                                    int M, int N, int K, int GX) {
    const int NJ = TN / 32;            // B-frags per wave
    __shared__ bf16 As[128 * 64];
    __shared__ bf16 Bs[TN * 64];

    // XCD-aware swizzle (grid size always % 8 == 0 here)
    int nwg = gridDim.x;
    int ld  = blockIdx.x;
    int wgid = (ld & 7) * (nwg >> 3) + (ld >> 3);
    int by = wgid / GX, bx = wgid % GX;

    int t = threadIdx.x, l = t & 63, w = t >> 6;
    int lr = l & 15, lg = l >> 4;
    size_t bm = (size_t)by * 128, bn = (size_t)bx * TN;

    int srow = t >> 3;           // 0..31
    int skb  = (t & 7) * 8;      // k elem offset
    const bf16* Ag = A  + (bm + srow) * K + skb;
    const bf16* Bg = Bw + (bn + srow) * K + skb;
    bf16* Asw = As + w * 512;    // per-wave uniform LDS base
    bf16* Bsw = Bs + w * 512;

    int wr = (w >> 1) << 6, wc = (w & 1) * (TN / 2);

    f32x4 acc[4][NJ];
    const f32x4 z4 = {0.f, 0.f, 0.f, 0.f};
    #pragma unroll
    for (int i = 0; i < 4; ++i)
        #pragma unroll
        for (int j = 0; j < NJ; ++j) acc[i][j] = z4;

    for (int k0 = 0; k0 < K; k0 += 64) {
        const bf16* Ak = Ag + k0;
        const bf16* Bk = Bg + k0;
        #pragma unroll
        for (int c = 0; c < 4; ++c)
            GLOAD_LDS16(Ak + (size_t)c * 32 * K, Asw + c * 2048);
        #pragma unroll
        for (int c = 0; c < NJ; ++c)
            GLOAD_LDS16(Bk + (size_t)c * 32 * K, Bsw + c * 2048);
        asm volatile("s_waitcnt vmcnt(0)" ::: "memory");
        __syncthreads();
        #pragma unroll
        for (int kk = 0; kk < 64; kk += 32) {
            s8 af[4], bfr[NJ];
            #pragma unroll
            for (int i = 0; i < 4; ++i)
                af[i] = *reinterpret_cast<const s8*>(As + (wr + i*16 + lr) * 64 + kk + lg * 8);
            #pragma unroll
            for (int j = 0; j < NJ; ++j)
                bfr[j] = *reinterpret_cast<const s8*>(Bs + (wc + j*16 + lr) * 64 + kk + lg * 8);
            #pragma unroll
            for (int i = 0; i < 4; ++i)
                #pragma unroll
                for (int j = 0; j < NJ; ++j)
                    acc[i][j] = __builtin_amdgcn_mfma_f32_16x16x32_bf16(af[i], bfr[j], acc[i][j], 0, 0, 0);
        }
        __syncthreads();
    }

    // epilogue: row = bm+wr+i*16+lg*4+q, col = bn+wc+j*16+lr
    float bias_v[NJ];
    if (EPI == 2 || EPI == 3) {
        #pragma unroll
        for (int j = 0; j < NJ; ++j) bias_v[j] = bias[bn + wc + j*16 + lr];
    }
    #pragma unroll
    for (int i = 0; i < 4; ++i) {
        #pragma unroll
        for (int q = 0; q < 4; ++q) {
            size_t rg = bm + wr + i*16 + lg*4 + q;
            #pragma unroll
            for (int j = 0; j < NJ; ++j) {
                size_t cg = bn + wc + j*16 + lr;
                float v = acc[i][j][q];
                if (EPI == 0) {
                    if (cg < 2048) {
                        Cb[rg * N + cg] = to_bf16(v);
                    } else {
                        int hd = (int)cg - 2048;
                        int hh = hd >> 6, d = hd & 63;
                        int bb = (int)(rg >> 11), sq = (int)(rg & 2047);
                        vT[(((size_t)(bb * NH_ + hh)) * HD_ + d) * S_ + sq] = to_bf16(v);
                    }
                } else if (EPI == 1) {
                    Cf[rg * N + cg] = v + res[rg * N + cg];
                } else if (EPI == 2) {
                    float u = v + bias_v[j];
                    u = 0.5f * u * (1.0f + erff(u * 0.70710678118654752f));
                    Cb[rg * N + cg] = to_bf16(u);
                } else {
                    Cf[rg * N + cg] = v + bias_v[j] + res[rg * N + cg];
                }
            }
        }
    }
}

// ---------------------------------------------------------------------------
// MFMA flash attention (causal). One q-tile = 64 q rows; 4 waves x 16 rows.
// KVBLK=64, 1-deep register prefetch of K/V, diagonal-only masking.
// K staged [64][72], V (pre-transposed in global) staged [64 d][72 kv],
// P per-wave [16][72]. fp32 online softmax. Q pre-scaled by 0.125 (exact).
// ---------------------------------------------------------------------------
__device__ __forceinline__ s8 scale_q8(s8 v) {
    union { s8 v; bf16 h[8]; } u; u.v = v;
    #pragma unroll
    for (int e = 0; e < 8; ++e)
        u.h[e] = to_bf16(__bfloat162float(u.h[e]) * 0.125f);
    return u.v;
}

__device__ __forceinline__ void attn_qtile(int qt, int h, int b, int t,
                                           const bf16* __restrict__ qkvb,
                                           const bf16* __restrict__ vT,
                                           bf16* __restrict__ ctx,
                                           bf16* Ks, bf16* Vt, bf16* Pw) {
    int l = t & 63, w = t >> 6, lr = l & 15, lg = l >> 4;
    int qb = qt * 64;

    const bf16* qp = qkvb + ((size_t)(b * S_) + qb + w * 16 + lr) * (3 * H_) + h * HD_;
    s8 qf0 = scale_q8(*reinterpret_cast<const s8*>(qp + lg * 8));
    s8 qf1 = scale_q8(*reinterpret_cast<const s8*>(qp + 32 + lg * 8));

    const f32x4 z4 = {0.f, 0.f, 0.f, 0.f};
    f32x4 oacc[4];
    #pragma unroll
    for (int n = 0; n < 4; ++n) oacc[n] = z4;
    float m_run[4] = {-1e30f, -1e30f, -1e30f, -1e30f};
    float l_run[4] = {0.f, 0.f, 0.f, 0.f};

    int skv = t >> 3, sd = (t & 7) * 8;     // K staging: rows skv, skv+32
    int vd  = t >> 2, vk = (t & 3) * 8;     // V staging: dim vd, kv vk, vk+32
    const bf16* kbase = qkvb + ((size_t)(b * S_) + skv) * (3 * H_) + H_ + h * HD_ + sd;
    const bf16* vbase = vT + ((size_t)((b * NH_ + h) * HD_) + vd) * S_ + vk;

    int nt = qt + 1;
    s8 k0 = *reinterpret_cast<const s8*>(kbase);
    s8 k1 = *reinterpret_cast<const s8*>(kbase + (size_t)32 * (3 * H_));
    s8 v0 = *reinterpret_cast<const s8*>(vbase);
    s8 v1 = *reinterpret_cast<const s8*>(vbase + 32);

    for (int it = 0; it < nt; ++it) {
        int kvb0 = it * 64;
        __syncthreads();   // prior tile's LDS reads complete
        *reinterpret_cast<s8*>(&Ks[skv * 72 + sd])        = k0;
        *reinterpret_cast<s8*>(&Ks[(skv + 32) * 72 + sd]) = k1;
        *reinterpret_cast<s8*>(&Vt[vd * 72 + vk])         = v0;
        *reinterpret_cast<s8*>(&Vt[vd * 72 + vk + 32])    = v1;
        int nx = (it + 1 < nt) ? kvb0 + 64 : kvb0;   // clamped prefetch
        k0 = *reinterpret_cast<const s8*>(kbase + (size_t)nx * (3 * H_));
        k1 = *reinterpret_cast<const s8*>(kbase + (size_t)(nx + 32) * (3 * H_));
        v0 = *reinterpret_cast<const s8*>(vbase + nx);
        v1 = *reinterpret_cast<const s8*>(vbase + nx + 32);
        __syncthreads();

        // QK^T: S[16 q][64 kv] per wave (Q pre-scaled)
        f32x4 sa[4];
        #pragma unroll
        for (int n = 0; n < 4; ++n) {
            f32x4 zz = z4;
            s8 kf0 = *reinterpret_cast<const s8*>(&Ks[(n*16 + lr) * 72 + lg * 8]);
            s8 kf1 = *reinterpret_cast<const s8*>(&Ks[(n*16 + lr) * 72 + 32 + lg * 8]);
            zz = __builtin_amdgcn_mfma_f32_16x16x32_bf16(qf0, kf0, zz, 0, 0, 0);
            zz = __builtin_amdgcn_mfma_f32_16x16x32_bf16(qf1, kf1, zz, 0, 0, 0);
            sa[n] = zz;
        }

        bool mask = (kvb0 + 64 > qb);   // block-uniform: diagonal tile only
        float p[4][4], mt[4];
        #pragma unroll
        for (int q = 0; q < 4; ++q) {
            #pragma unroll
            for (int n = 0; n < 4; ++n) {
                float s = sa[n][q];
                if (mask) {
                    int col  = kvb0 + n*16 + lr;
                    int qrow = qb + w*16 + lg*4 + q;
                    s = (col <= qrow) ? s : -1e30f;
                }
                p[n][q] = s;
            }
            mt[q] = fmaxf(fmaxf(p[0][q], p[1][q]), fmaxf(p[2][q], p[3][q]));
        }
        #pragma unroll
        for (int m = 1; m < 16; m <<= 1) {
            #pragma unroll
            for (int q = 0; q < 4; ++q) mt[q] = fmaxf(mt[q], __shfl_xor(mt[q], m, 64));
        }
        float al[4], ps[4];
        #pragma unroll
        for (int q = 0; q < 4; ++q) {
            float mn = fmaxf(m_run[q], mt[q]);
            al[q] = __expf(m_run[q] - mn);
            m_run[q] = mn;
            float e0 = __expf(p[0][q] - mn), e1 = __expf(p[1][q] - mn);
            float e2 = __expf(p[2][q] - mn), e3 = __expf(p[3][q] - mn);
            p[0][q] = e0; p[1][q] = e1; p[2][q] = e2; p[3][q] = e3;
            ps[q] = (e0 + e1) + (e2 + e3);
        }
        #pragma unroll
        for (int m = 1; m < 16; m <<= 1) {
            #pragma unroll
            for (int q = 0; q < 4; ++q) ps[q] += __shfl_xor(ps[q], m, 64);
        }
        #pragma unroll
        for (int q = 0; q < 4; ++q) {
            l_run[q] = l_run[q] * al[q] + ps[q];
            #pragma unroll
            for (int n = 0; n < 4; ++n) {
                oacc[n][q] *= al[q];
                Pw[(lg*4 + q) * 72 + n*16 + lr] = to_bf16(p[n][q]);
            }
        }
        asm volatile("s_waitcnt lgkmcnt(0)" ::: "memory");
        __builtin_amdgcn_sched_barrier(0);

        // PV: O[16][64] += P[16][64] @ V[64][64]
        #pragma unroll
        for (int ks = 0; ks < 2; ++ks) {
            s8 pf = *reinterpret_cast<const s8*>(&Pw[lr * 72 + ks*32 + lg * 8]);
            #pragma unroll
            for (int n = 0; n < 4; ++n) {
                s8 vf = *reinterpret_cast<const s8*>(&Vt[(n*16 + lr) * 72 + ks*32 + lg * 8]);
                oacc[n] = __builtin_amdgcn_mfma_f32_16x16x32_bf16(pf, vf, oacc[n], 0, 0, 0);
            }
        }
    }

    #pragma unroll
    for (int q = 0; q < 4; ++q) {
        float inv = 1.0f / l_run[q];
        size_t row = (size_t)(b * S_) + qb + w * 16 + lg * 4 + q;
        #pragma unroll
        for (int n = 0; n < 4; ++n)
            ctx[row * H_ + h * HD_ + n * 16 + lr] = to_bf16(oacc[n][q] * inv);
    }
}

__global__ __launch_bounds__(256) void attn_mfma(const bf16* __restrict__ qkvb,
                                                 const bf16* __restrict__ vT,
                                                 bf16* __restrict__ ctx) {
    __shared__ bf16 Ks[64 * 72];
    __shared__ bf16 Vt[64 * 72];
    __shared__ bf16 Pw[4][16 * 72];
    int h = blockIdx.y, b = blockIdx.z, t = threadIdx.x;
    int w = t >> 6;
    // causal pairing: tiles (i, NQT-1-i) -> constant work per block
    attn_qtile(blockIdx.x,           h, b, t, qkvb, vT, ctx, Ks, Vt, Pw[w]);
    attn_qtile(NQT - 1 - blockIdx.x, h, b, t, qkvb, vT, ctx, Ks, Vt, Pw[w]);
}

// ---------------------------------------------------------------------------
extern "C" void kernel_launch(void* const* d_in, const int* in_sizes, int n_in,
                              void* d_out, int out_size, void* d_ws, size_t ws_size,
                              hipStream_t stream) {
    const float* x     = (const float*)d_in[0];
    const float* ln1_g = (const float*)d_in[2];
    const float* ln1_b = (const float*)d_in[3];
    const float* ln2_g = (const float*)d_in[4];
    const float* ln2_b = (const float*)d_in[5];
    const float* qkv_w = (const float*)d_in[6];
    const float* out_w = (const float*)d_in[7];
    const float* fc1_w = (const float*)d_in[8];
    const float* fc1_b = (const float*)d_in[9];
    const float* fc2_w = (const float*)d_in[10];
    const float* fc2_b = (const float*)d_in[11];
    float* out = (float*)d_out;

    bf16* w_qkv  = (bf16*)d_ws;                       // 3*H*H
    bf16* w_out  = w_qkv  + (size_t)3*H_*H_;          // H*H
    bf16* w_fc1  = w_out  + (size_t)H_*H_;            // DFF*H
    bf16* w_fc2  = w_fc1  + (size_t)DFF_*H_;          // H*DFF
    bf16* h_bf   = w_fc2  + (size_t)H_*DFF_;          // ROWS*H
    bf16* qkv_bf = h_bf   + (size_t)ROWS*H_;          // ROWS*3H
    bf16* vTb    = qkv_bf + (size_t)ROWS*3*H_;        // B*NH*HD*S
    bf16* ctx_bf = vTb    + (size_t)B_*NH_*HD_*S_;    // ROWS*H
    bf16* ff_bf  = ctx_bf + (size_t)ROWS*H_;          // ROWS*DFF

    // fused weight casts (12.58M elems / 8 per thread / 256 per block = 6144)
    cast_all<<<6144, 256, 0, stream>>>(qkv_w, out_w, fc1_w, fc2_w,
                                       w_qkv, w_out, w_fc1, w_fc2);

    // 1. h = LN1(x) -> bf16
    ln_bf16<<<ROWS, 256, 0, stream>>>(x, ln1_g, ln1_b, h_bf);
    // 2. qkv = h @ qkv_w^T  (Q,K row-major bf16; V written transposed to vT)
    gemm_bf16<0,128><<<32 * 24, 256, 0, stream>>>(h_bf, w_qkv, qkv_bf, nullptr, vTb,
                                                  nullptr, nullptr, ROWS, 3*H_, H_, 24);
    // 3. ctx = causal flash attention (bf16 MFMA, paired q-tiles)
    attn_mfma<<<dim3(NQT/2, NH_, B_), 256, 0, stream>>>(qkv_bf, vTb, ctx_bf);
    // 4. x1 = x + ctx @ out_w^T -> d_out (fp32)
    gemm_bf16<1,64><<<32 * 16, 256, 0, stream>>>(ctx_bf, w_out, nullptr, out, nullptr,
                                                 nullptr, x, ROWS, H_, H_, 16);
    // 5. h2 = LN2(x1) -> bf16
    ln_bf16<<<ROWS, 256, 0, stream>>>(out, ln2_g, ln2_b, h_bf);
    // 6. ff = gelu(h2 @ fc1_w^T + fc1_b) -> bf16
    gemm_bf16<2,128><<<32 * 32, 256, 0, stream>>>(h_bf, w_fc1, ff_bf, nullptr, nullptr,
                                                  fc1_b, nullptr, ROWS, DFF_, H_, 32);
    // 7. out = x1 + ff @ fc2_w^T + fc2_b (fp32, reads d_out as residual)
    gemm_bf16<3,64><<<32 * 16, 256, 0, stream>>>(ff_bf, w_fc2, nullptr, out, nullptr,
                                                 fc2_b, out, ROWS, H_, DFF_, 16);
}